// Round 17
// baseline (70.162 us; speedup 1.0000x reference)
//
#include <hip/hip_runtime.h>

typedef __bf16 bf16;
typedef _Float16 f16;
typedef f16 f16x4 __attribute__((ext_vector_type(4)));
typedef f16 f16x8 __attribute__((ext_vector_type(8)));
typedef float f32x4 __attribute__((ext_vector_type(4)));

#define MFMA_FP(a, b, c) __builtin_amdgcn_mfma_f32_16x16x32_f16((a), (b), (c), 0, 0, 0)

static constexpr int Bn = 8, T = 2048, C = 1024, H = 128;
static constexpr int M = Bn * T; // 16384

// direct global->LDS, 16B per lane (lds dest is wave-uniform base + lane*16)
__device__ __forceinline__ void gll16(const void* g, void* l) {
  __builtin_amdgcn_global_load_lds(
      (const __attribute__((address_space(1))) unsigned int*)g,
      (__attribute__((address_space(3))) unsigned int*)l, 16, 0, 0);
}

// ---------------------------------------------------------------------------
// Kernel 0: transpose  W[C][H] fp32 -> wt [3][H][C] fp16
// ---------------------------------------------------------------------------
__global__ __launch_bounds__(256) void kwt(const float* __restrict__ Wq,
                                           const float* __restrict__ Wk,
                                           const float* __restrict__ Wv,
                                           f16* __restrict__ wt) {
  __shared__ float tl[32][33];
  const int w = blockIdx.z;
  const float* src = (w == 0) ? Wq : (w == 1) ? Wk : Wv;
  f16* dh = wt + (size_t)w * H * C;
  const int k0 = blockIdx.x * 32, n0 = blockIdx.y * 32;
  const int tx = threadIdx.x & 31, ty = threadIdx.x >> 5; // 32 x 8
  for (int i = ty; i < 32; i += 8) tl[i][tx] = src[(size_t)(k0 + i) * H + n0 + tx];
  __syncthreads();
  for (int i = ty; i < 32; i += 8)
    dh[(size_t)(n0 + i) * C + k0 + tx] = (f16)tl[tx][i];
}

// ---------------------------------------------------------------------------
// Kernel 1: QKV projection — EXACT R9 configuration (best measured: ~35us).
// Single-buffer, global_load_lds width-16 both operands, 2 barriers/step,
// grid (M/64, 3) = 768 blocks = 3/CU; TLP covers the per-step drain.
// ---------------------------------------------------------------------------
__global__ __launch_bounds__(256) void proj_kernel(const float* __restrict__ x,
                                                   const f16* __restrict__ wt,
                                                   f16* __restrict__ qo,
                                                   f16* __restrict__ ko,
                                                   f16* __restrict__ vt) {
  __shared__ __align__(16) float As[64 * 64];   // [m][k] f32, swizzled, 16KB
  __shared__ __align__(16) f16  Bs[128 * 64];   // [n][k] f16, swizzled, 16KB
  const int tid = threadIdx.x;
  const int lane = tid & 63, g = lane >> 4, r16 = lane & 15;
  const int wave = tid >> 6, wr = wave >> 1, wc = wave & 1;
  const int m0 = blockIdx.x * 64;
  const int which = blockIdx.y;
  const f16* wh = wt + (size_t)which * H * C;

  int asrc[4], bsrc[4];
  int aldu[4], bldu[4];
#pragma unroll
  for (int i = 0; i < 4; ++i) {
    const int u = wave * 4 + i;
    const int ra = u * 4 + (lane >> 4);
    asrc[i] = (m0 + ra) * C + (((lane & 15) ^ (ra & 7)) << 2);
    aldu[i] = u * 256;
    const int rb = u * 8 + (lane >> 3);
    bsrc[i] = rb * C + (((lane & 7) ^ (rb & 7)) << 3);
    bldu[i] = u * 512;
  }

  f32x4 acc[2][4] = {};

#define ISSUE(K0)                                                  \
  _Pragma("unroll")                                                \
  for (int i = 0; i < 4; ++i) {                                    \
    gll16(&x[asrc[i] + (K0)], &As[aldu[i]]);                       \
    gll16(&wh[bsrc[i] + (K0)], &Bs[bldu[i]]);                      \
  }

  ISSUE(0);
  for (int k0 = 0; k0 < C; k0 += 64) {
    __syncthreads();
#pragma unroll
    for (int kb = 0; kb < 2; ++kb) {
      f16x8 af[2], bf[4];
#pragma unroll
      for (int mt = 0; mt < 2; ++mt) {
        const int r = wr * 32 + mt * 16 + r16;
        const int s = r & 7;
        const f32x4 a0 = *(const f32x4*)&As[r * 64 + (((kb * 8 + g * 2) ^ s) << 2)];
        const f32x4 a1 = *(const f32x4*)&As[r * 64 + (((kb * 8 + g * 2 + 1) ^ s) << 2)];
#pragma unroll
        for (int j = 0; j < 4; ++j) { af[mt][j] = (f16)a0[j]; af[mt][4 + j] = (f16)a1[j]; }
      }
#pragma unroll
      for (int nt = 0; nt < 4; ++nt) {
        const int r = wc * 64 + nt * 16 + r16;
        const int phys = (kb * 4 + g) ^ (r & 7);
        bf[nt] = *(const f16x8*)&Bs[r * 64 + phys * 8];
      }
#pragma unroll
      for (int mt = 0; mt < 2; ++mt)
#pragma unroll
        for (int nt = 0; nt < 4; ++nt)
          acc[mt][nt] = MFMA_FP(af[mt], bf[nt], acc[mt][nt]);
    }
    __syncthreads();
    if (k0 + 64 < C) ISSUE(k0 + 64);
  }
#undef ISSUE

  if (which < 2) {
    f16* dst = which ? ko : qo;
#pragma unroll
    for (int mt = 0; mt < 2; ++mt)
#pragma unroll
      for (int nt = 0; nt < 4; ++nt) {
        const int mb = m0 + wr * 32 + mt * 16 + g * 4;
        const int col = wc * 64 + nt * 16 + r16;
#pragma unroll
        for (int r = 0; r < 4; ++r)
          dst[(size_t)(mb + r) * H + col] = (f16)acc[mt][nt][r];
      }
  } else {
    const int b = m0 >> 11;
    const int tb0 = m0 & 2047;
    f16* vbase = vt + (size_t)b * H * T;
#pragma unroll
    for (int mt = 0; mt < 2; ++mt)
#pragma unroll
      for (int nt = 0; nt < 4; ++nt) {
        const int tib = tb0 + wr * 32 + mt * 16 + g * 4;
        const int h = wc * 64 + nt * 16 + r16;
        f16x4 pk;
#pragma unroll
        for (int r = 0; r < 4; ++r) pk[r] = (f16)acc[mt][nt][r];
        *(f16x4*)&vbase[(size_t)h * T + tib] = pk;
      }
  }
}

// ---------------------------------------------------------------------------
// Kernel 2: causal flash attention, QB=128 rows/block, 8 waves (512 thr),
// 4-way s-parity split.  512 blocks = ALL co-resident (2/CU, 50KB LDS):
//   b = bb&7 (XCD-pinned); t2 = bb>>3; t2<32: qt = 15-(t2>>2) (heavy half),
//   t2>=32: qt = (t2-32)>>2 (light half) -> resident pairs sum qt+qt' = 15.
//   par = t2&3; tiles j = par, par+4, ... <= 2qt+1.
// Single-buffer K/V (16KB each), reg-prefetch next tile during compute,
// 2 barriers/tile.  Waves fully masked by causality skip compute (uniform).
// Each staged tile now feeds 128 q-rows (2x R16) -> ~45% fewer stagings.
// par0 writes self-normalized O (f32) to out; par1..3 to oS; combine merges.
// ---------------------------------------------------------------------------
__global__ __launch_bounds__(512, 4) void attn_kernel(const f16* __restrict__ qp,
                                                      const f16* __restrict__ kp,
                                                      const f16* __restrict__ vp,
                                                      float* __restrict__ out,
                                                      f16* __restrict__ oS,
                                                      float* __restrict__ MLs) {
  __shared__ __align__(16) f16 KS[64 * 128];    // [s][h], chunk-swizzled
  __shared__ __align__(16) f16 VS[128 * 64];    // [h][s], chunk-swizzled
  __shared__ __align__(16) f16 Pl[8][16][72];   // per-wave P [q][s], padded

  const int tid = threadIdx.x, lane = tid & 63, wave = tid >> 6;  // wave 0..7
  const int g = lane >> 4, q15 = lane & 15;
  const int x7 = q15 & 7;
  const int bb = blockIdx.x;
  const int b = bb & 7;
  const int t2 = bb >> 3;                        // 0..63
  const int qt = (t2 < 32) ? (15 - (t2 >> 2)) : ((t2 - 32) >> 2);
  const int par = t2 & 3;
  const int q0 = qt * 128;
  const int qrow = q0 + wave * 16 + q15;
  const int task = b * 16 + qt;
  const int jmax = 2 * qt + 1;
  const int n = (jmax >= par) ? ((jmax - par) >> 2) + 1 : 0;

  const f16* qb = qp + (size_t)b * T * H;
  const f16* kb = kp + (size_t)b * T * H;
  const f16* vb = vp + (size_t)b * H * T;

  // staging: K 16 units of 1KB (4 s-rows x 256B), V 16 units (8 h-rows x 128B);
  // 8 waves stage 2 units each.  Linear LDS dest; source chunk pre-XOR'd.
  int koff[2], voff[2], lo[2];
#pragma unroll
  for (int i = 0; i < 2; ++i) {
    const int u = wave * 2 + i;
    const int rK = u * 4 + (lane >> 4);
    koff[i] = rK * H + (((lane & 15) ^ (rK & 7)) << 3);
    const int hV = u * 8 + (lane >> 3);
    voff[i] = hV * T + (((lane & 7) ^ (hV & 7)) << 3);
    lo[i] = u * 512 + lane * 8;
  }

  f16x8 qf[4];
#pragma unroll
  for (int k4 = 0; k4 < 4; ++k4)
    qf[k4] = *(const f16x8*)&qb[(size_t)qrow * H + k4 * 32 + g * 8];

  f32x4 o[8] = {};
  float mrun = -1e30f, lrun = 0.f;

  f16x8 rk[2], rv[2];
#define LOADT(S0)                                                   \
  _Pragma("unroll")                                                 \
  for (int i = 0; i < 2; ++i) {                                     \
    rk[i] = *(const f16x8*)&kb[(size_t)(S0) * H + koff[i]];         \
    rv[i] = *(const f16x8*)&vb[(size_t)(S0) + voff[i]];             \
  }
#define WRITET()                                                    \
  _Pragma("unroll")                                                 \
  for (int i = 0; i < 2; ++i) {                                     \
    *(f16x8*)&KS[lo[i]] = rk[i];                                    \
    *(f16x8*)&VS[lo[i]] = rv[i];                                    \
  }

  if (n > 0) {
    LOADT(par * 64);
    WRITET();
    __syncthreads();

    for (int kk = 0; kk < n; ++kk) {
      const int s0 = (par + 4 * kk) * 64;
      if (kk + 1 < n) LOADT(s0 + 256);      // reg prefetch (T14 issue-early)

      // waves whose entire row-range is masked skip compute (wave-uniform)
      if (s0 <= q0 + wave * 16 + 15) {
        f32x4 sacc[4] = {};
#pragma unroll
        for (int mt = 0; mt < 4; ++mt) {
          const int row = mt * 16 + q15;
#pragma unroll
          for (int k4 = 0; k4 < 4; ++k4) {
            const int pch = (k4 * 4 + g) ^ (row & 7);
            const f16x8 kf = *(const f16x8*)&KS[row * 128 + pch * 8];
            sacc[mt] = MFMA_FP(kf, qf[k4], sacc[mt]);
          }
        }
        if (s0 + 63 > q0 + wave * 16) {     // diagonal-spanning tile: mask
#pragma unroll
          for (int mt = 0; mt < 4; ++mt)
#pragma unroll
            for (int r = 0; r < 4; ++r)
              if (s0 + mt * 16 + g * 4 + r > qrow) sacc[mt][r] = -1e30f;
        }
        float tmax = -1e30f;
#pragma unroll
        for (int mt = 0; mt < 4; ++mt)
#pragma unroll
          for (int r = 0; r < 4; ++r) tmax = fmaxf(tmax, sacc[mt][r]);
        tmax = fmaxf(tmax, __shfl_xor(tmax, 16));
        tmax = fmaxf(tmax, __shfl_xor(tmax, 32));
        if (!__all(tmax <= mrun + 8.f)) {   // defer-max (T13)
          const float mnew = fmaxf(mrun, tmax);
          const float alpha = __expf(mrun - mnew);
          lrun *= alpha;
#pragma unroll
          for (int i = 0; i < 8; ++i) o[i] *= alpha;
          mrun = mnew;
        }
        float lt = 0.f;
#pragma unroll
        for (int mt = 0; mt < 4; ++mt) {
          f16x4 pk;
#pragma unroll
          for (int r = 0; r < 4; ++r) {
            const float p = __expf(sacc[mt][r] - mrun);
            lt += p;
            pk[r] = (f16)p;
          }
          *(f16x4*)&Pl[wave][q15][mt * 16 + g * 4] = pk;
        }
        lt += __shfl_xor(lt, 16);
        lt += __shfl_xor(lt, 32);
        lrun += lt;
        const f16x8 pf0 = *(const f16x8*)&Pl[wave][q15][g * 8];
        const f16x8 pf1 = *(const f16x8*)&Pl[wave][q15][32 + g * 8];
#pragma unroll
        for (int mt = 0; mt < 8; ++mt) {
          const int h = mt * 16 + q15;
          const f16x8 vf0 = *(const f16x8*)&VS[h * 64 + ((g ^ x7) << 3)];
          o[mt] = MFMA_FP(vf0, pf0, o[mt]);
          const f16x8 vf1 = *(const f16x8*)&VS[h * 64 + (((4 + g) ^ x7) << 3)];
          o[mt] = MFMA_FP(vf1, pf1, o[mt]);
        }
      }

      if (kk + 1 < n) {
        __syncthreads();   // all reads of current tile done
        WRITET();          // commit prefetched tile
        __syncthreads();   // tile ready
      }
    }
  }
#undef LOADT
#undef WRITET

  const float inv = (lrun > 0.f) ? 1.0f / lrun : 0.f;
  if (lane < 16) {
    MLs[((size_t)(task * 4 + par) * 128 + wave * 16 + lane) * 2 + 0] = mrun;
    MLs[((size_t)(task * 4 + par) * 128 + wave * 16 + lane) * 2 + 1] = lrun;
  }
  if (par == 0) {
    float* ob = out + ((size_t)b * T + qrow) * H;
#pragma unroll
    for (int mt = 0; mt < 8; ++mt) {
      f32x4 pk;
#pragma unroll
      for (int r = 0; r < 4; ++r) pk[r] = o[mt][r] * inv;
      *(f32x4*)&ob[mt * 16 + g * 4] = pk;
    }
  } else {
    f16* sb = oS + ((size_t)(task * 3 + par - 1) * 128 + wave * 16 + q15) * 128;
#pragma unroll
    for (int mt = 0; mt < 8; ++mt) {
      f16x4 pk;
#pragma unroll
      for (int r = 0; r < 4; ++r) pk[r] = (f16)(o[mt][r] * inv);
      *(f16x4*)&sb[mt * 16 + g * 4] = pk;
    }
  }
}

// ---------------------------------------------------------------------------
// Kernel 3: 4-way flash merge per task (128 rows), in-place on d_out.
// 128 blocks x 256 thr: thread = (row = tid>>1, 64-col half).
// ---------------------------------------------------------------------------
__global__ __launch_bounds__(256) void combine_kernel(float* __restrict__ out,
                                                      const f16* __restrict__ oS,
                                                      const float* __restrict__ MLs) {
  const int task = blockIdx.x;            // b*16 + qt
  const int b = task >> 4, qt = task & 15;
  const int tid = threadIdx.x;
  const int row = tid >> 1;
  const int cb = (tid & 1) * 64;
  float m[4], l[4];
#pragma unroll
  for (int p = 0; p < 4; ++p) {
    m[p] = MLs[((size_t)(task * 4 + p) * 128 + row) * 2 + 0];
    l[p] = MLs[((size_t)(task * 4 + p) * 128 + row) * 2 + 1];
  }
  const float Mg = fmaxf(fmaxf(m[0], m[1]), fmaxf(m[2], m[3]));
  float w[4], sum = 0.f;
#pragma unroll
  for (int p = 0; p < 4; ++p) { w[p] = l[p] * __expf(m[p] - Mg); sum += w[p]; }
  const float inv = 1.0f / sum;
  float* orow = out + ((size_t)b * T + qt * 128 + row) * H + cb;
  const f16* s1 = oS + ((size_t)(task * 3 + 0) * 128 + row) * 128 + cb;
  const f16* s2 = oS + ((size_t)(task * 3 + 1) * 128 + row) * 128 + cb;
  const f16* s3 = oS + ((size_t)(task * 3 + 2) * 128 + row) * 128 + cb;
#pragma unroll
  for (int c = 0; c < 64; c += 8) {
    const f16x8 o1 = *(const f16x8*)&s1[c];
    const f16x8 o2 = *(const f16x8*)&s2[c];
    const f16x8 o3 = *(const f16x8*)&s3[c];
    f32x4 a0 = *(const f32x4*)&orow[c];
    f32x4 a1 = *(const f32x4*)&orow[c + 4];
    f32x4 r0, r1;
#pragma unroll
    for (int r = 0; r < 4; ++r) {
      r0[r] = (w[0] * a0[r] + w[1] * (float)o1[r] + w[2] * (float)o2[r] + w[3] * (float)o3[r]) * inv;
      r1[r] = (w[0] * a1[r] + w[1] * (float)o1[4 + r] + w[2] * (float)o2[4 + r] + w[3] * (float)o3[4 + r]) * inv;
    }
    *(f32x4*)&orow[c] = r0;
    *(f32x4*)&orow[c + 4] = r1;
  }
}

// ---------------------------------------------------------------------------
extern "C" void kernel_launch(void* const* d_in, const int* in_sizes, int n_in,
                              void* d_out, int out_size, void* d_ws, size_t ws_size,
                              hipStream_t stream) {
  const float* x  = (const float*)d_in[0];   // fp32 inputs per reference
  const float* Wq = (const float*)d_in[1];
  const float* Wk = (const float*)d_in[2];
  const float* Wv = (const float*)d_in[3];
  float* out = (float*)d_out;                // fp32 output

  f16*  wt  = (f16*)d_ws;                              // 3*H*C fp16
  f16*  qf  = wt + (size_t)3 * H * C;                  // M*H fp16
  f16*  kf  = qf + (size_t)M * H;                      // M*H fp16
  f16*  vf  = kf + (size_t)M * H;                      // M*H fp16 [b][h][t]
  f16*  oS  = vf + (size_t)M * H;                      // 128*3*128*128 fp16
  float* MLs = (float*)(oS + (size_t)128 * 3 * 128 * 128); // 128*4*128*2 f32

  kwt<<<dim3(C / 32, H / 32, 3), 256, 0, stream>>>(Wq, Wk, Wv, wt);
  proj_kernel<<<dim3(M / 64, 3), 256, 0, stream>>>(x, wt, qf, kf, vf);
  attn_kernel<<<512, 512, 0, stream>>>(qf, kf, vf, out, oS, MLs);
  combine_kernel<<<128, 256, 0, stream>>>(out, oS, MLs);
}